// Round 7
// baseline (4240.913 us; speedup 1.0000x reference)
//
#include <hip/hip_runtime.h>
#include <cstdint>

typedef unsigned short u16;
typedef unsigned int u32;
typedef __attribute__((ext_vector_type(8))) short short8v;
typedef __attribute__((ext_vector_type(4))) float float4v;

#define MFMA16 __builtin_amdgcn_mfma_f32_16x16x32_bf16

__device__ __forceinline__ u16 f2bf(float x) {
    union { float f; u32 u; } c; c.f = x;
    return (u16)((c.u + 0x7FFFu + ((c.u >> 16) & 1u)) >> 16);
}
__device__ __forceinline__ float bf2f(u16 h) {
    union { u32 u; float f; } c; c.u = ((u32)h) << 16;
    return c.f;
}

// global -> LDS direct DMA, 16B per lane. dest must be wave-uniform base.
__device__ __forceinline__ void dma16(const void* g, void* l) {
    __builtin_amdgcn_global_load_lds(
        (const __attribute__((address_space(1))) u32*)g,
        (__attribute__((address_space(3))) u32*)l, 16, 0, 0);
}

// ===================== zero page init =====================
__global__ void zinit(u32* p) { p[threadIdx.x] = 0u; }   // 256 thr -> 1024 B

// ===================== weight prep =====================
// dst layout: [tap][ic][p][kg][M][8], value = split_p( W[m][ic*32+kg*8+j][tap] )
__global__ __launch_bounds__(256)
void prep_w(const float* __restrict__ W, u16* __restrict__ dst,
            int M, int cin, int nIC, int TAPS, int total)
{
    int e = blockIdx.x * 256 + threadIdx.x;
    if (e >= total) return;
    int tmp = e;
    int j = tmp & 7; tmp >>= 3;
    int m = tmp % M; tmp /= M;
    int kg = tmp & 3; tmp >>= 2;
    int p = tmp & 1; tmp >>= 1;
    int ic = tmp % nIC;
    int tap = tmp / nIC;
    int i = ic * 32 + kg * 8 + j;
    float val = (i < cin) ? W[((size_t)m * cin + i) * TAPS + tap] : 0.f;
    u16 h = f2bf(val);
    dst[e] = p ? f2bf(val - bf2f(h)) : h;
}

// ===================== adjacency: block 0 (from raw x) =====================
__global__ __launch_bounds__(256)
void adj0(const float* __restrict__ x, const float* __restrict__ Am,
          u16* __restrict__ dstb, long dst_nstride, int dst_poff)
{
    __shared__ float A_s[25][26];
    for (int i2 = threadIdx.x; i2 < 625; i2 += 256) A_s[i2 / 25][i2 % 25] = Am[i2];
    __syncthreads();
    int t = blockIdx.x * 256 + threadIdx.x;
    int nl = blockIdx.y;
    if (t >= 300) return;
    const float* xp = x + ((size_t)nl * 300 + t) * 75;
    float acc[25][3];
#pragma unroll
    for (int w = 0; w < 25; ++w) { acc[w][0] = 0.f; acc[w][1] = 0.f; acc[w][2] = 0.f; }
    for (int v = 0; v < 25; ++v) {
        float x0 = xp[v * 3 + 0], x1 = xp[v * 3 + 1], x2 = xp[v * 3 + 2];
#pragma unroll
        for (int w = 0; w < 25; ++w) {
            float a = A_s[v][w];
            acc[w][0] = fmaf(a, x0, acc[w][0]);
            acc[w][1] = fmaf(a, x1, acc[w][1]);
            acc[w][2] = fmaf(a, x2, acc[w][2]);
        }
    }
    u16* dhi = dstb + (size_t)nl * dst_nstride;
    u16* dlo = dhi + dst_poff;
#pragma unroll
    for (int w = 0; w < 25; ++w) {
        u16 hb[32], lb[32];
#pragma unroll
        for (int c = 0; c < 32; ++c) { hb[c] = 0; lb[c] = 0; }
#pragma unroll
        for (int c = 0; c < 3; ++c) {
            float y = acc[w][c];
            u16 h = f2bf(y);
            hb[c] = h; lb[c] = f2bf(y - bf2f(h));
        }
        size_t o = ((size_t)w * 300 + t) * 32;
#pragma unroll
        for (int q = 0; q < 4; ++q) {
            *(uint4*)&dhi[o + q * 8] = *(const uint4*)&hb[q * 8];
            *(uint4*)&dlo[o + q * 8] = *(const uint4*)&lb[q * 8];
        }
    }
}

// ===================== adjacency: in-place on F =====================
__global__ __launch_bounds__(256)
void adj_ip(u16* fb, const float* __restrict__ Am, int C, int Tin,
            long nstride, int poff)
{
    __shared__ float A_s[25][26];
    for (int i2 = threadIdx.x; i2 < 625; i2 += 256) A_s[i2 / 25][i2 % 25] = Am[i2];
    __syncthreads();
    const int C4 = C >> 2;
    int idx = blockIdx.x * 256 + threadIdx.x;
    if (idx >= Tin * C4) return;
    int t = idx / C4;
    int c = (idx - t * C4) * 4;
    u16* hi = fb + (size_t)blockIdx.y * nstride;
    u16* lo = hi + poff;
    float a0[25], a1[25], a2[25], a3[25];
#pragma unroll
    for (int w = 0; w < 25; ++w) { a0[w] = 0.f; a1[w] = 0.f; a2[w] = 0.f; a3[w] = 0.f; }
    for (int v = 0; v < 25; ++v) {
        size_t o = (size_t)(v * Tin + t) * C + c;
        ushort4 h4 = *(const ushort4*)&hi[o];
        ushort4 l4 = *(const ushort4*)&lo[o];
        float y0 = bf2f(h4.x) + bf2f(l4.x);
        float y1 = bf2f(h4.y) + bf2f(l4.y);
        float y2 = bf2f(h4.z) + bf2f(l4.z);
        float y3 = bf2f(h4.w) + bf2f(l4.w);
#pragma unroll
        for (int w = 0; w < 25; ++w) {
            float a = A_s[v][w];
            a0[w] = fmaf(a, y0, a0[w]);
            a1[w] = fmaf(a, y1, a1[w]);
            a2[w] = fmaf(a, y2, a2[w]);
            a3[w] = fmaf(a, y3, a3[w]);
        }
    }
#pragma unroll
    for (int w = 0; w < 25; ++w) {
        size_t o = (size_t)(w * Tin + t) * C + c;
        ushort4 ho, lo4; u16 h;
        h = f2bf(a0[w]); ho.x = h; lo4.x = f2bf(a0[w] - bf2f(h));
        h = f2bf(a1[w]); ho.y = h; lo4.y = f2bf(a1[w] - bf2f(h));
        h = f2bf(a2[w]); ho.z = h; lo4.z = f2bf(a2[w] - bf2f(h));
        h = f2bf(a3[w]); ho.w = h; lo4.w = f2bf(a3[w] - bf2f(h));
        *(ushort4*)&hi[o] = ho;
        *(ushort4*)&lo[o] = lo4;
    }
}

// ===================== conv-GEMM via MFMA (split bf16), DMA-staged =====================
// dst[o][v][t'] = relu( sum_{i,k} W[o][i][k] * src[i][v][t'*S + k - PAD] )
// B: global_load_lds double-buffer, sigma part-swizzle (source+read), zero-page halo.
// A: per-tap direct global->reg loads (L2-broadcast; NO banked prefetch arrays --
//    rounds 5/6 proved hand-banking spills to scratch: 0.5 GB writes/dispatch).
// S==2 windows phase-split so fragment reads step 1 LDS row (2-way banks).
template<int VW, int NT, int TAPS, int S, int OUTF32>
__global__ __launch_bounds__(256, 2)
void conv5(const u16* __restrict__ srcb, const u16* __restrict__ wtp,
           u16* __restrict__ dstb, float* __restrict__ outb,
           int K, int M, int Tin, int Tout,
           long src_nstride, int src_poff, long dst_nstride, int dst_poff,
           int o_tiles, int strips, int cnt, const u16* __restrict__ zpage)
{
    constexpr int PADW = (TAPS == 1) ? 0 : 4;
    constexpr int NPH = (S == 2) ? 2 : 1;
    constexpr int RAW = (TAPS == 1) ? NT : ((S == 1) ? NT + 8 : NT + 4);
    constexpr int RQ = 32 / (VW * NPH);
    constexpr int R = ((RAW + RQ - 1) / RQ) * RQ;       // rows per phase (padded)
    constexpr int NF = NT / 16;
    constexpr int NB = (VW * 2 * NPH * R * 4) / 256;    // 16B chunks per thread
    static_assert((VW * 2 * NPH * R * 4) % 256 == 0, "chunk mult");
    constexpr int BUF_U16 = VW * 2 * NPH * R * 32;
    constexpr int PL_STRIDE = NPH * R * 32;             // u16 between planes
    constexpr int EP = (VW == 2) ? 34 : 18;
    constexpr int SMEM_B = 2 * BUF_U16 * 2;
    static_assert(VW * NT * EP * 4 <= SMEM_B, "E fits");
    static_assert(SMEM_B <= 65536, "LDS limit");
    __shared__ __align__(16) char smem[SMEM_B];
    u16* Bs = (u16*)smem;
    float* E = (float*)smem;

    const int tid = threadIdx.x;
    const int l15 = tid & 15;
    const int lkg = (tid >> 4) & 3;
    const int wv = tid >> 6;
    const int vh = (VW == 2) ? (wv >> 1) : wv;
    const int oh = (VW == 2) ? (wv & 1) : 0;

    // ---- bijective XCD-chunked work id; ot fastest, nl, strip, vg slowest ----
    int Wk;
    {
        const int nwg = gridDim.x;
        int q8 = nwg >> 3, r8 = nwg & 7;
        int xcd = blockIdx.x & 7, bl = blockIdx.x >> 3;
        Wk = (xcd < r8 ? xcd * (q8 + 1) : r8 * (q8 + 1) + (xcd - r8) * q8) + bl;
    }
    const int ot = Wk % o_tiles; int r0 = Wk / o_tiles;
    const int nl = r0 % cnt; r0 /= cnt;
    const int strip = r0 % strips;
    const int vg = r0 / strips;

    const int t0 = strip * NT;
    const int wstart = t0 * S - PADW;
    const int nIC = K >> 5;
    const int obase = (VW == 2) ? (ot * 128 + oh * 64 + l15) : (ot * 64 + l15);

    const u16* shi = srcb + (size_t)nl * src_nstride;
    const u16* slo = shi + src_poff;

    float4v acc[4][NF];
#pragma unroll
    for (int mt = 0; mt < 4; ++mt)
#pragma unroll
        for (int nf = 0; nf < NF; ++nf) acc[mt][nf] = (float4v)0.f;

    // ---- per-chunk B source pointers (ic-invariant; +ic*64 bytes per chunk) ----
    const char* bptr[NB];
#pragma unroll
    for (int k = 0; k < NB; ++k) {
        int d = k * 256 + tid;
        int part = d & 3; int d2 = d >> 2;
        int rw = d2 % R; d2 /= R;
        int ph = (NPH == 2) ? (d2 % NPH) : 0; d2 /= NPH;
        int pl = d2 & 1; int w2 = d2 >> 1;
        int v = vg * VW + w2;
        int t = (S == 2) ? (wstart + 2 * rw + ph) : (wstart + rw);
        int psrc = (part - (rw >> 1)) & 3;
        bool ok = (v < 25) && (t >= 0) && (t < Tin);
        const u16* base = pl ? slo : shi;
        bptr[k] = ok ? (const char*)(base + ((size_t)(v * Tin + t) * K + psrc * 8))
                     : (const char*)zpage;
    }

    auto stage = [&](int buf, int ic) {
        u16* base = Bs + buf * BUF_U16 + (tid & 192) * 8;  // wave-uniform lane-0 dest
#pragma unroll
        for (int k = 0; k < NB; ++k)
            dma16(bptr[k] + (size_t)ic * 64, base + k * 2048);
    };
    auto prefA = [&](uint4(&a)[8], int tap, int ic) {
        const u16* base = wtp + (size_t)(tap * nIC + ic) * (64 * M);
#pragma unroll
        for (int pl = 0; pl < 2; ++pl)
#pragma unroll
            for (int mt = 0; mt < 4; ++mt)
                a[pl * 4 + mt] = *(const uint4*)(base + ((size_t)(pl * 4 + lkg) * M + obase + mt * 16) * 8);
    };
    auto ctap = [&](const uint4(&a)[8], int tap, int buf) {
        const u16* bb0 = Bs + buf * BUF_U16;
#pragma unroll
        for (int nf = 0; nf < NF; ++nf) {
            const int tt = nf * 16 + l15;
            const int rw = (S == 2) ? (tt + (tap >> 1)) : (tt + tap);
            const int ph = (S == 2) ? (tap & 1) : 0;
            const int sl = (lkg + (rw >> 1)) & 3;
            const u16* p = bb0 + (size_t)(((vh * 2 * NPH + ph) * R + rw) * 4 + sl) * 8;
            short8v bh = *(const short8v*)p;
            short8v bl = *(const short8v*)(p + PL_STRIDE);
#pragma unroll
            for (int mt = 0; mt < 4; ++mt) {
                short8v ah = __builtin_bit_cast(short8v, a[mt]);
                short8v al = __builtin_bit_cast(short8v, a[4 + mt]);
                acc[mt][nf] = MFMA16(ah, bh, acc[mt][nf], 0, 0, 0);
                acc[mt][nf] = MFMA16(ah, bl, acc[mt][nf], 0, 0, 0);
                acc[mt][nf] = MFMA16(al, bh, acc[mt][nf], 0, 0, 0);
            }
        }
    };

    {
        stage(0, 0);
        __syncthreads();
        int cur = 0;
#pragma unroll 1
        for (int ic = 0; ic < nIC; ++ic) {
            if (ic + 1 < nIC) stage(cur ^ 1, ic + 1);
#pragma unroll
            for (int t = 0; t < TAPS; ++t) {
                uint4 a[8];
                prefA(a, t, ic);
                ctap(a, t, cur);
            }
            __syncthreads();   // drains next-buffer DMA; frees cur buffer
            cur ^= 1;
        }
    }

    // ---- epilogue: per 16-o group, LDS transpose (E overlays B), relu, store ----
    u16* dhi = dstb ? dstb + (size_t)nl * dst_nstride : nullptr;
    u16* dlo = dhi ? dhi + dst_poff : nullptr;
    float* outn = OUTF32 ? outb + (size_t)nl * 480000 : nullptr;
#pragma unroll
    for (int m = 0; m < 4; ++m) {
        __syncthreads();
#pragma unroll
        for (int nf = 0; nf < NF; ++nf)
#pragma unroll
            for (int r = 0; r < 4; ++r)
                E[(vh * NT + nf * 16 + l15) * EP + ((VW == 2) ? oh * 16 : 0) + lkg * 4 + r] = acc[m][nf][r];
        __syncthreads();
        if (!OUTF32) {
            constexpr int C16 = (VW == 2) ? 2 : 1;
            for (int q = tid; q < VW * NT * C16; q += 256) {
                int row = q / C16, c16 = q - row * C16;
                int vv = vg * VW + row / NT;
                int tl = row % NT, tg = t0 + tl;
                if (vv < 25 && tg < Tout) {
                    u16 hb[16], lb[16];
#pragma unroll
                    for (int j = 0; j < 16; ++j) {
                        float y = fmaxf(E[row * EP + c16 * 16 + j], 0.f);
                        u16 h = f2bf(y); hb[j] = h; lb[j] = f2bf(y - bf2f(h));
                    }
                    int ob = ot * (VW == 2 ? 128 : 64) + c16 * 64 + m * 16;
                    size_t o = (size_t)(vv * Tout + tg) * M + ob;
                    *(uint4*)&dhi[o] = *(const uint4*)&hb[0];
                    *(uint4*)&dhi[o + 8] = *(const uint4*)&hb[8];
                    *(uint4*)&dlo[o] = *(const uint4*)&lb[0];
                    *(uint4*)&dlo[o + 8] = *(const uint4*)&lb[8];
                }
            }
        } else {
            for (int q = tid; q < 32 * NT; q += 256) {
                int ol = q / NT, tl = q - ol * NT, tg = t0 + tl;
                if (tg < Tout) {
                    int o = ot * 128 + (ol >> 4) * 64 + m * 16 + (ol & 15);
                    float* op = outn + (size_t)o * 1875 + tg * 25 + vg * 2;
#pragma unroll
                    for (int v2 = 0; v2 < 2; ++v2)
                        if (vg * 2 + v2 < 25)
                            op[v2] = fmaxf(E[(v2 * NT + tl) * EP + ol], 0.f);
                }
            }
        }
    }
}

// ===================== host =====================
extern "C" void kernel_launch(void* const* d_in, const int* in_sizes, int n_in,
                              void* d_out, int out_size, void* d_ws, size_t ws_size,
                              hipStream_t stream)
{
    const float* x = (const float*)d_in[0];
    const float* A = (const float*)d_in[1];
    const float* WS[10];
    const float* WT[10];
    for (int i = 0; i < 10; ++i) {
        WS[i] = (const float*)d_in[2 + 2 * i];
        WT[i] = (const float*)d_in[3 + 2 * i];
    }
    float* outF = (float*)d_out;

    static const int KM[10]  = {32, 64, 64, 64, 64, 128, 128, 128, 256, 256};
    static const int MM[10]  = {64, 64, 64, 64, 128, 128, 128, 256, 256, 256};
    static const int TIN[10] = {300, 300, 300, 300, 300, 150, 150, 150, 75, 75};
    static const int SS[10]  = {1, 1, 1, 1, 2, 1, 1, 2, 1, 1};

    // d_ws: [zero page 1024B][prep weights][spill activation zone]
    const u16* zpage = (const u16*)d_ws;
    zinit<<<1, 256, 0, stream>>>((u32*)d_ws);

    size_t mixoff[10], wtoff[10], off = 0;
    for (int b = 0; b < 10; ++b) {
        mixoff[b] = off; off += (size_t)(KM[b] / 32) * 64 * MM[b];
        wtoff[b] = off;  off += (size_t)9 * (MM[b] / 32) * 64 * MM[b];
    }
    u16* prep = (u16*)((char*)d_ws + 1024);
    size_t prep_bytes = ((off * 2 + 255) / 256) * 256;
    u16* ws_s = (u16*)((char*)d_ws + 1024 + prep_bytes);
    size_t ws_spill = (ws_size > prep_bytes + 1024) ? ws_size - prep_bytes - 1024 : 0;

    for (int b = 0; b < 10; ++b) {
        int nICm = KM[b] / 32;
        int totm = nICm * 64 * MM[b];
        prep_w<<<(totm + 255) / 256, 256, 0, stream>>>(
            WS[b], prep + mixoff[b], MM[b], (b == 0 ? 3 : KM[b]), nICm, 1, totm);
        int nICt = MM[b] / 32;
        int tott = 9 * nICt * 64 * MM[b];
        prep_w<<<(tott + 255) / 256, 256, 0, stream>>>(
            WT[b], prep + wtoff[b], MM[b], MM[b], nICt, 9, tott);
    }

    const long F_STR = 960000;
    const long S_STR = 1920000;
    const size_t F_PN_B = 1920000;
    const size_t S_PN_B = 3840000;
    const size_t dout_b = (size_t)out_size * 4;

    int done = 0;
    while (done < 64) {
        size_t used = (size_t)done * F_PN_B;
        size_t dout_rem = dout_b - used;
        int NC = (int)((dout_rem + ws_spill) / (F_PN_B + S_PN_B));
        if (NC > 64 - done) NC = 64 - done;
        if (NC < 1) NC = 1;
        int k_s = 0;
        for (;; --NC) {
            long rem_after_F = (long)dout_rem - (long)NC * (long)F_PN_B;
            k_s = rem_after_F > 0 ? (int)(rem_after_F / (long)S_PN_B) : 0;
            if (k_s > NC) k_s = NC;
            if ((size_t)(NC - k_s) * S_PN_B <= ws_spill) break;
            if (NC <= 1) { NC = 1; k_s = 0; break; }
        }
        u16* Fz = (u16*)d_out + used / 2;
        u16* Sd = (u16*)d_out + (used + (size_t)NC * F_PN_B) / 2;

        for (int b = 0; b < 10; ++b) {
            const int K = KM[b], M = MM[b], Tin = TIN[b], S = SS[b];
            const int Tout = (S == 1) ? Tin : Tin / 2;
            const int fpoff = (b == 0) ? 240000 : 480000;
            const int spoff = 25 * Tin * M;

            if (b == 0)
                adj0<<<dim3(2, NC), 256, 0, stream>>>(
                    x + (size_t)done * 22500, A, Fz, F_STR, 240000);
            else {
                int thr = Tin * (K >> 2);
                adj_ip<<<dim3((thr + 255) / 256, NC), 256, 0, stream>>>(
                    Fz, A, K, Tin, F_STR, 480000);
            }

            for (int part = 0; part < 2; ++part) {
                int n0 = part ? k_s : 0;
                int cnt = part ? NC - k_s : k_s;
                if (cnt <= 0) continue;
                u16* sb = part ? ws_s : Sd;
                u16* fb = Fz + (size_t)n0 * F_STR;

                // ---- mix (TAPS=1): fb -> sb ----
                if (b <= 3) {
                    const int otm = 1, strips = 5;   // VW4, NT64, T=300
                    conv5<4, 64, 1, 1, 0><<<otm * 7 * strips * cnt, 256, 0, stream>>>(
                        fb, prep + mixoff[b], sb, nullptr, K, M, Tin, Tin,
                        F_STR, fpoff, S_STR, spoff, otm, strips, cnt, zpage);
                } else {
                    const int otm = M / 128, strips = (Tin + 79) / 80;  // VW2, NT80
                    conv5<2, 80, 1, 1, 0><<<otm * 13 * strips * cnt, 256, 0, stream>>>(
                        fb, prep + mixoff[b], sb, nullptr, K, M, Tin, Tin,
                        F_STR, fpoff, S_STR, spoff, otm, strips, cnt, zpage);
                }

                // ---- temporal (TAPS=9): sb -> fb (or out for b9) ----
                if (b <= 3) {
                    const int ott = 1, strips = (Tin + 47) / 48;        // VW4, NT48
                    conv5<4, 48, 9, 1, 0><<<ott * 7 * strips * cnt, 256, 0, stream>>>(
                        sb, prep + wtoff[b], fb, nullptr, M, M, Tin, Tout,
                        S_STR, spoff, F_STR, 480000, ott, strips, cnt, zpage);
                } else if (S == 2) {
                    const int ott = M / 128, strips = (Tout + 47) / 48; // VW2, NT48
                    conv5<2, 48, 9, 2, 0><<<ott * 13 * strips * cnt, 256, 0, stream>>>(
                        sb, prep + wtoff[b], fb, nullptr, M, M, Tin, Tout,
                        S_STR, spoff, F_STR, 480000, ott, strips, cnt, zpage);
                } else if (b == 9) {
                    const int ott = 2, strips = 1;                      // VW2, NT80, f32 out
                    conv5<2, 80, 9, 1, 1><<<ott * 13 * strips * cnt, 256, 0, stream>>>(
                        sb, prep + wtoff[b], nullptr,
                        outF + (size_t)(done + n0) * 480000,
                        M, M, Tin, Tout, S_STR, spoff, 0, 0, ott, strips, cnt, zpage);
                } else {
                    const int ott = M / 128, strips = (Tout + 79) / 80; // VW2, NT80
                    conv5<2, 80, 9, 1, 0><<<ott * 13 * strips * cnt, 256, 0, stream>>>(
                        sb, prep + wtoff[b], fb, nullptr, M, M, Tin, Tout,
                        S_STR, spoff, F_STR, 480000, ott, strips, cnt, zpage);
                }
            }
        }
        done += NC;
    }
}

// Round 8
// 4090.623 us; speedup vs baseline: 1.0367x; 1.0367x over previous
//
#include <hip/hip_runtime.h>
#include <cstdint>

typedef unsigned short u16;
typedef unsigned int u32;
typedef __attribute__((ext_vector_type(8))) short short8v;
typedef __attribute__((ext_vector_type(4))) float float4v;

#define MFMA16 __builtin_amdgcn_mfma_f32_16x16x32_bf16

__device__ __forceinline__ u16 f2bf(float x) {
    union { float f; u32 u; } c; c.f = x;
    return (u16)((c.u + 0x7FFFu + ((c.u >> 16) & 1u)) >> 16);
}
__device__ __forceinline__ float bf2f(u16 h) {
    union { u32 u; float f; } c; c.u = ((u32)h) << 16;
    return c.f;
}

// global -> LDS direct DMA, 16B per lane. dest must be wave-uniform base.
__device__ __forceinline__ void dma16(const void* g, void* l) {
    __builtin_amdgcn_global_load_lds(
        (const __attribute__((address_space(1))) u32*)g,
        (__attribute__((address_space(3))) u32*)l, 16, 0, 0);
}

// ===================== zero page init =====================
__global__ void zinit(u32* p) { p[threadIdx.x] = 0u; }   // 256 thr -> 1024 B

// ===================== weight prep =====================
// dst layout: [tap][ic][p][kg][M][8], value = split_p( W[m][ic*32+kg*8+j][tap] )
__global__ __launch_bounds__(256)
void prep_w(const float* __restrict__ W, u16* __restrict__ dst,
            int M, int cin, int nIC, int TAPS, int total)
{
    int e = blockIdx.x * 256 + threadIdx.x;
    if (e >= total) return;
    int tmp = e;
    int j = tmp & 7; tmp >>= 3;
    int m = tmp % M; tmp /= M;
    int kg = tmp & 3; tmp >>= 2;
    int p = tmp & 1; tmp >>= 1;
    int ic = tmp % nIC;
    int tap = tmp / nIC;
    int i = ic * 32 + kg * 8 + j;
    float val = (i < cin) ? W[((size_t)m * cin + i) * TAPS + tap] : 0.f;
    u16 h = f2bf(val);
    dst[e] = p ? f2bf(val - bf2f(h)) : h;
}

// ===================== adjacency: block 0 (from raw x) =====================
__global__ __launch_bounds__(256)
void adj0(const float* __restrict__ x, const float* __restrict__ Am,
          u16* __restrict__ dstb, long dst_nstride, int dst_poff)
{
    __shared__ float A_s[25][26];
    for (int i2 = threadIdx.x; i2 < 625; i2 += 256) A_s[i2 / 25][i2 % 25] = Am[i2];
    __syncthreads();
    int t = blockIdx.x * 256 + threadIdx.x;
    int nl = blockIdx.y;
    if (t >= 300) return;
    const float* xp = x + ((size_t)nl * 300 + t) * 75;
    float acc[25][3];
#pragma unroll
    for (int w = 0; w < 25; ++w) { acc[w][0] = 0.f; acc[w][1] = 0.f; acc[w][2] = 0.f; }
    for (int v = 0; v < 25; ++v) {
        float x0 = xp[v * 3 + 0], x1 = xp[v * 3 + 1], x2 = xp[v * 3 + 2];
#pragma unroll
        for (int w = 0; w < 25; ++w) {
            float a = A_s[v][w];
            acc[w][0] = fmaf(a, x0, acc[w][0]);
            acc[w][1] = fmaf(a, x1, acc[w][1]);
            acc[w][2] = fmaf(a, x2, acc[w][2]);
        }
    }
    u16* dhi = dstb + (size_t)nl * dst_nstride;
    u16* dlo = dhi + dst_poff;
#pragma unroll
    for (int w = 0; w < 25; ++w) {
        u16 hb[32], lb[32];
#pragma unroll
        for (int c = 0; c < 32; ++c) { hb[c] = 0; lb[c] = 0; }
#pragma unroll
        for (int c = 0; c < 3; ++c) {
            float y = acc[w][c];
            u16 h = f2bf(y);
            hb[c] = h; lb[c] = f2bf(y - bf2f(h));
        }
        size_t o = ((size_t)w * 300 + t) * 32;
#pragma unroll
        for (int q = 0; q < 4; ++q) {
            *(uint4*)&dhi[o + q * 8] = *(const uint4*)&hb[q * 8];
            *(uint4*)&dlo[o + q * 8] = *(const uint4*)&lb[q * 8];
        }
    }
}

// ===================== adjacency: in-place on F =====================
__global__ __launch_bounds__(256)
void adj_ip(u16* fb, const float* __restrict__ Am, int C, int Tin,
            long nstride, int poff)
{
    __shared__ float A_s[25][26];
    for (int i2 = threadIdx.x; i2 < 625; i2 += 256) A_s[i2 / 25][i2 % 25] = Am[i2];
    __syncthreads();
    const int C4 = C >> 2;
    int idx = blockIdx.x * 256 + threadIdx.x;
    if (idx >= Tin * C4) return;
    int t = idx / C4;
    int c = (idx - t * C4) * 4;
    u16* hi = fb + (size_t)blockIdx.y * nstride;
    u16* lo = hi + poff;
    float a0[25], a1[25], a2[25], a3[25];
#pragma unroll
    for (int w = 0; w < 25; ++w) { a0[w] = 0.f; a1[w] = 0.f; a2[w] = 0.f; a3[w] = 0.f; }
    for (int v = 0; v < 25; ++v) {
        size_t o = (size_t)(v * Tin + t) * C + c;
        ushort4 h4 = *(const ushort4*)&hi[o];
        ushort4 l4 = *(const ushort4*)&lo[o];
        float y0 = bf2f(h4.x) + bf2f(l4.x);
        float y1 = bf2f(h4.y) + bf2f(l4.y);
        float y2 = bf2f(h4.z) + bf2f(l4.z);
        float y3 = bf2f(h4.w) + bf2f(l4.w);
#pragma unroll
        for (int w = 0; w < 25; ++w) {
            float a = A_s[v][w];
            a0[w] = fmaf(a, y0, a0[w]);
            a1[w] = fmaf(a, y1, a1[w]);
            a2[w] = fmaf(a, y2, a2[w]);
            a3[w] = fmaf(a, y3, a3[w]);
        }
    }
#pragma unroll
    for (int w = 0; w < 25; ++w) {
        size_t o = (size_t)(w * Tin + t) * C + c;
        ushort4 ho, lo4; u16 h;
        h = f2bf(a0[w]); ho.x = h; lo4.x = f2bf(a0[w] - bf2f(h));
        h = f2bf(a1[w]); ho.y = h; lo4.y = f2bf(a1[w] - bf2f(h));
        h = f2bf(a2[w]); ho.z = h; lo4.z = f2bf(a2[w] - bf2f(h));
        h = f2bf(a3[w]); ho.w = h; lo4.w = f2bf(a3[w] - bf2f(h));
        *(ushort4*)&hi[o] = ho;
        *(ushort4*)&lo[o] = lo4;
    }
}

// ===================== conv-GEMM via MFMA (split bf16), DMA-staged =====================
// dst[o][v][t'] = relu( sum_{i,k} W[o][i][k] * src[i][v][t'*S + k - PAD] )
// B: global_load_lds double-buffer, sigma part-swizzle (source+read), zero-page halo.
// A: 2-bank ping-pong register prefetch, one tap ahead (prefA(next) issued BEFORE
//    ctap(cur) so L2 latency hides under the MFMA cluster). 2 banks = ~64 VGPR --
//    fits under the compiler's 128-VGPR choice; 3 banks (round 6) spilled.
// S==2 windows phase-split so fragment reads step 1 LDS row (2-way banks).
template<int VW, int NT, int TAPS, int S, int OUTF32>
__global__ __launch_bounds__(256, 2)
void conv6(const u16* __restrict__ srcb, const u16* __restrict__ wtp,
           u16* __restrict__ dstb, float* __restrict__ outb,
           int K, int M, int Tin, int Tout,
           long src_nstride, int src_poff, long dst_nstride, int dst_poff,
           int o_tiles, int strips, int cnt, const u16* __restrict__ zpage)
{
    constexpr int PADW = (TAPS == 1) ? 0 : 4;
    constexpr int NPH = (S == 2) ? 2 : 1;
    constexpr int RAW = (TAPS == 1) ? NT : ((S == 1) ? NT + 8 : NT + 4);
    constexpr int RQ = 32 / (VW * NPH);
    constexpr int R = ((RAW + RQ - 1) / RQ) * RQ;       // rows per phase (padded)
    constexpr int NF = NT / 16;
    constexpr int NB = (VW * 2 * NPH * R * 4) / 256;    // 16B chunks per thread
    static_assert((VW * 2 * NPH * R * 4) % 256 == 0, "chunk mult");
    constexpr int BUF_U16 = VW * 2 * NPH * R * 32;
    constexpr int PL_STRIDE = NPH * R * 32;             // u16 between planes
    constexpr int EP = (VW == 2) ? 34 : 18;
    constexpr int SMEM_B = 2 * BUF_U16 * 2;
    static_assert(VW * NT * EP * 4 <= SMEM_B, "E fits");
    static_assert(SMEM_B <= 65536, "LDS limit");
    __shared__ __align__(16) char smem[SMEM_B];
    u16* Bs = (u16*)smem;
    float* E = (float*)smem;

    const int tid = threadIdx.x;
    const int l15 = tid & 15;
    const int lkg = (tid >> 4) & 3;
    const int wv = tid >> 6;
    const int vh = (VW == 2) ? (wv >> 1) : wv;
    const int oh = (VW == 2) ? (wv & 1) : 0;

    // ---- bijective XCD-chunked work id; ot fastest, nl, strip, vg slowest ----
    int Wk;
    {
        const int nwg = gridDim.x;
        int q8 = nwg >> 3, r8 = nwg & 7;
        int xcd = blockIdx.x & 7, bl = blockIdx.x >> 3;
        Wk = (xcd < r8 ? xcd * (q8 + 1) : r8 * (q8 + 1) + (xcd - r8) * q8) + bl;
    }
    const int ot = Wk % o_tiles; int r0 = Wk / o_tiles;
    const int nl = r0 % cnt; r0 /= cnt;
    const int strip = r0 % strips;
    const int vg = r0 / strips;

    const int t0 = strip * NT;
    const int wstart = t0 * S - PADW;
    const int nIC = K >> 5;
    const int obase = (VW == 2) ? (ot * 128 + oh * 64 + l15) : (ot * 64 + l15);

    const u16* shi = srcb + (size_t)nl * src_nstride;
    const u16* slo = shi + src_poff;

    float4v acc[4][NF];
#pragma unroll
    for (int mt = 0; mt < 4; ++mt)
#pragma unroll
        for (int nf = 0; nf < NF; ++nf) acc[mt][nf] = (float4v)0.f;

    // ---- per-chunk B source pointers (ic-invariant; +ic*64 bytes per chunk) ----
    const char* bptr[NB];
#pragma unroll
    for (int k = 0; k < NB; ++k) {
        int d = k * 256 + tid;
        int part = d & 3; int d2 = d >> 2;
        int rw = d2 % R; d2 /= R;
        int ph = (NPH == 2) ? (d2 % NPH) : 0; d2 /= NPH;
        int pl = d2 & 1; int w2 = d2 >> 1;
        int v = vg * VW + w2;
        int t = (S == 2) ? (wstart + 2 * rw + ph) : (wstart + rw);
        int psrc = (part - (rw >> 1)) & 3;
        bool ok = (v < 25) && (t >= 0) && (t < Tin);
        const u16* base = pl ? slo : shi;
        bptr[k] = ok ? (const char*)(base + ((size_t)(v * Tin + t) * K + psrc * 8))
                     : (const char*)zpage;
    }

    auto stage = [&](int buf, int ic) {
        u16* base = Bs + buf * BUF_U16 + (tid & 192) * 8;  // wave-uniform lane-0 dest
#pragma unroll
        for (int k = 0; k < NB; ++k)
            dma16(bptr[k] + (size_t)ic * 64, base + k * 2048);
    };
    auto prefA = [&](uint4(&a)[8], int tap, int ic) {
        const u16* base = wtp + (size_t)(tap * nIC + ic) * (64 * M);
#pragma unroll
        for (int pl = 0; pl < 2; ++pl)
#pragma unroll
            for (int mt = 0; mt < 4; ++mt)
                a[pl * 4 + mt] = *(const uint4*)(base + ((size_t)(pl * 4 + lkg) * M + obase + mt * 16) * 8);
    };
    auto ctap = [&](const uint4(&a)[8], int tap, int buf) {
        const u16* bb0 = Bs + buf * BUF_U16;
#pragma unroll
        for (int nf = 0; nf < NF; ++nf) {
            const int tt = nf * 16 + l15;
            const int rw = (S == 2) ? (tt + (tap >> 1)) : (tt + tap);
            const int ph = (S == 2) ? (tap & 1) : 0;
            const int sl = (lkg + (rw >> 1)) & 3;
            const u16* p = bb0 + (size_t)(((vh * 2 * NPH + ph) * R + rw) * 4 + sl) * 8;
            short8v bh = *(const short8v*)p;
            short8v bl = *(const short8v*)(p + PL_STRIDE);
#pragma unroll
            for (int mt = 0; mt < 4; ++mt) {
                short8v ah = __builtin_bit_cast(short8v, a[mt]);
                short8v al = __builtin_bit_cast(short8v, a[4 + mt]);
                acc[mt][nf] = MFMA16(ah, bh, acc[mt][nf], 0, 0, 0);
                acc[mt][nf] = MFMA16(ah, bl, acc[mt][nf], 0, 0, 0);
                acc[mt][nf] = MFMA16(al, bh, acc[mt][nf], 0, 0, 0);
            }
        }
    };

    {
        uint4 aA[8], aB[8];
        stage(0, 0);
        prefA(aA, 0, 0);
        __syncthreads();
        int cur = 0;
#pragma unroll 1
        for (int ic = 0; ic < nIC; ++ic) {
            const int icn = (ic + 1 < nIC) ? ic + 1 : ic;
            if (ic + 1 < nIC) stage(cur ^ 1, ic + 1);
#pragma unroll
            for (int t = 0; t < TAPS; ++t) {
                const int tn = (t + 1 < TAPS) ? t + 1 : 0;
                const int ici = (t + 1 < TAPS) ? ic : icn;
                if ((t & 1) == 0) { prefA(aB, tn, ici); ctap(aA, t, cur); }
                else              { prefA(aA, tn, ici); ctap(aB, t, cur); }
            }
            if ((TAPS & 1) != 0) {    // odd TAPS: next tap-0 bank landed in aB
#pragma unroll
                for (int j = 0; j < 8; ++j) aA[j] = aB[j];
            }
            __syncthreads();   // drains next-buffer DMA; frees cur buffer
            cur ^= 1;
        }
    }

    // ---- epilogue: per 16-o group, LDS transpose (E overlays B), relu, store ----
    u16* dhi = dstb ? dstb + (size_t)nl * dst_nstride : nullptr;
    u16* dlo = dhi ? dhi + dst_poff : nullptr;
    float* outn = OUTF32 ? outb + (size_t)nl * 480000 : nullptr;
#pragma unroll
    for (int m = 0; m < 4; ++m) {
        __syncthreads();
#pragma unroll
        for (int nf = 0; nf < NF; ++nf)
#pragma unroll
            for (int r = 0; r < 4; ++r)
                E[(vh * NT + nf * 16 + l15) * EP + ((VW == 2) ? oh * 16 : 0) + lkg * 4 + r] = acc[m][nf][r];
        __syncthreads();
        if (!OUTF32) {
            constexpr int C16 = (VW == 2) ? 2 : 1;
            for (int q = tid; q < VW * NT * C16; q += 256) {
                int row = q / C16, c16 = q - row * C16;
                int vv = vg * VW + row / NT;
                int tl = row % NT, tg = t0 + tl;
                if (vv < 25 && tg < Tout) {
                    u16 hb[16], lb[16];
#pragma unroll
                    for (int j = 0; j < 16; ++j) {
                        float y = fmaxf(E[row * EP + c16 * 16 + j], 0.f);
                        u16 h = f2bf(y); hb[j] = h; lb[j] = f2bf(y - bf2f(h));
                    }
                    int ob = ot * (VW == 2 ? 128 : 64) + c16 * 64 + m * 16;
                    size_t o = (size_t)(vv * Tout + tg) * M + ob;
                    *(uint4*)&dhi[o] = *(const uint4*)&hb[0];
                    *(uint4*)&dhi[o + 8] = *(const uint4*)&hb[8];
                    *(uint4*)&dlo[o] = *(const uint4*)&lb[0];
                    *(uint4*)&dlo[o + 8] = *(const uint4*)&lb[8];
                }
            }
        } else {
            for (int q = tid; q < 32 * NT; q += 256) {
                int ol = q / NT, tl = q - ol * NT, tg = t0 + tl;
                if (tg < Tout) {
                    int o = ot * 128 + (ol >> 4) * 64 + m * 16 + (ol & 15);
                    float* op = outn + (size_t)o * 1875 + tg * 25 + vg * 2;
#pragma unroll
                    for (int v2 = 0; v2 < 2; ++v2)
                        if (vg * 2 + v2 < 25)
                            op[v2] = fmaxf(E[(v2 * NT + tl) * EP + ol], 0.f);
                }
            }
        }
    }
}

// ===================== host =====================
extern "C" void kernel_launch(void* const* d_in, const int* in_sizes, int n_in,
                              void* d_out, int out_size, void* d_ws, size_t ws_size,
                              hipStream_t stream)
{
    const float* x = (const float*)d_in[0];
    const float* A = (const float*)d_in[1];
    const float* WS[10];
    const float* WT[10];
    for (int i = 0; i < 10; ++i) {
        WS[i] = (const float*)d_in[2 + 2 * i];
        WT[i] = (const float*)d_in[3 + 2 * i];
    }
    float* outF = (float*)d_out;

    static const int KM[10]  = {32, 64, 64, 64, 64, 128, 128, 128, 256, 256};
    static const int MM[10]  = {64, 64, 64, 64, 128, 128, 128, 256, 256, 256};
    static const int TIN[10] = {300, 300, 300, 300, 300, 150, 150, 150, 75, 75};
    static const int SS[10]  = {1, 1, 1, 1, 2, 1, 1, 2, 1, 1};

    // d_ws: [zero page 1024B][prep weights][spill activation zone]
    const u16* zpage = (const u16*)d_ws;
    zinit<<<1, 256, 0, stream>>>((u32*)d_ws);

    size_t mixoff[10], wtoff[10], off = 0;
    for (int b = 0; b < 10; ++b) {
        mixoff[b] = off; off += (size_t)(KM[b] / 32) * 64 * MM[b];
        wtoff[b] = off;  off += (size_t)9 * (MM[b] / 32) * 64 * MM[b];
    }
    u16* prep = (u16*)((char*)d_ws + 1024);
    size_t prep_bytes = ((off * 2 + 255) / 256) * 256;
    u16* ws_s = (u16*)((char*)d_ws + 1024 + prep_bytes);
    size_t ws_spill = (ws_size > prep_bytes + 1024) ? ws_size - prep_bytes - 1024 : 0;

    for (int b = 0; b < 10; ++b) {
        int nICm = KM[b] / 32;
        int totm = nICm * 64 * MM[b];
        prep_w<<<(totm + 255) / 256, 256, 0, stream>>>(
            WS[b], prep + mixoff[b], MM[b], (b == 0 ? 3 : KM[b]), nICm, 1, totm);
        int nICt = MM[b] / 32;
        int tott = 9 * nICt * 64 * MM[b];
        prep_w<<<(tott + 255) / 256, 256, 0, stream>>>(
            WT[b], prep + wtoff[b], MM[b], MM[b], nICt, 9, tott);
    }

    const long F_STR = 960000;
    const long S_STR = 1920000;
    const size_t F_PN_B = 1920000;
    const size_t S_PN_B = 3840000;
    const size_t dout_b = (size_t)out_size * 4;

    int done = 0;
    while (done < 64) {
        size_t used = (size_t)done * F_PN_B;
        size_t dout_rem = dout_b - used;
        int NC = (int)((dout_rem + ws_spill) / (F_PN_B + S_PN_B));
        if (NC > 64 - done) NC = 64 - done;
        if (NC < 1) NC = 1;
        int k_s = 0;
        for (;; --NC) {
            long rem_after_F = (long)dout_rem - (long)NC * (long)F_PN_B;
            k_s = rem_after_F > 0 ? (int)(rem_after_F / (long)S_PN_B) : 0;
            if (k_s > NC) k_s = NC;
            if ((size_t)(NC - k_s) * S_PN_B <= ws_spill) break;
            if (NC <= 1) { NC = 1; k_s = 0; break; }
        }
        u16* Fz = (u16*)d_out + used / 2;
        u16* Sd = (u16*)d_out + (used + (size_t)NC * F_PN_B) / 2;

        for (int b = 0; b < 10; ++b) {
            const int K = KM[b], M = MM[b], Tin = TIN[b], S = SS[b];
            const int Tout = (S == 1) ? Tin : Tin / 2;
            const int fpoff = (b == 0) ? 240000 : 480000;
            const int spoff = 25 * Tin * M;

            if (b == 0)
                adj0<<<dim3(2, NC), 256, 0, stream>>>(
                    x + (size_t)done * 22500, A, Fz, F_STR, 240000);
            else {
                int thr = Tin * (K >> 2);
                adj_ip<<<dim3((thr + 255) / 256, NC), 256, 0, stream>>>(
                    Fz, A, K, Tin, F_STR, 480000);
            }

            for (int part = 0; part < 2; ++part) {
                int n0 = part ? k_s : 0;
                int cnt = part ? NC - k_s : k_s;
                if (cnt <= 0) continue;
                u16* sb = part ? ws_s : Sd;
                u16* fb = Fz + (size_t)n0 * F_STR;

                // ---- mix (TAPS=1): fb -> sb ----
                if (b <= 3) {
                    const int otm = 1, strips = 5;   // VW4, NT64, T=300
                    conv6<4, 64, 1, 1, 0><<<otm * 7 * strips * cnt, 256, 0, stream>>>(
                        fb, prep + mixoff[b], sb, nullptr, K, M, Tin, Tin,
                        F_STR, fpoff, S_STR, spoff, otm, strips, cnt, zpage);
                } else {
                    const int otm = M / 128, strips = (Tin + 79) / 80;  // VW2, NT80
                    conv6<2, 80, 1, 1, 0><<<otm * 13 * strips * cnt, 256, 0, stream>>>(
                        fb, prep + mixoff[b], sb, nullptr, K, M, Tin, Tin,
                        F_STR, fpoff, S_STR, spoff, otm, strips, cnt, zpage);
                }

                // ---- temporal (TAPS=9): sb -> fb (or out for b9) ----
                if (b <= 3) {
                    const int ott = 1, strips = (Tin + 47) / 48;        // VW4, NT48
                    conv6<4, 48, 9, 1, 0><<<ott * 7 * strips * cnt, 256, 0, stream>>>(
                        sb, prep + wtoff[b], fb, nullptr, M, M, Tin, Tout,
                        S_STR, spoff, F_STR, 480000, ott, strips, cnt, zpage);
                } else if (S == 2) {
                    const int ott = M / 128, strips = (Tout + 47) / 48; // VW2, NT48
                    conv6<2, 48, 9, 2, 0><<<ott * 13 * strips * cnt, 256, 0, stream>>>(
                        sb, prep + wtoff[b], fb, nullptr, M, M, Tin, Tout,
                        S_STR, spoff, F_STR, 480000, ott, strips, cnt, zpage);
                } else if (b == 9) {
                    const int ott = 2, strips = 1;                      // VW2, NT80, f32 out
                    conv6<2, 80, 9, 1, 1><<<ott * 13 * strips * cnt, 256, 0, stream>>>(
                        sb, prep + wtoff[b], nullptr,
                        outF + (size_t)(done + n0) * 480000,
                        M, M, Tin, Tout, S_STR, spoff, 0, 0, ott, strips, cnt, zpage);
                } else {
                    const int ott = M / 128, strips = (Tout + 79) / 80; // VW2, NT80
                    conv6<2, 80, 9, 1, 0><<<ott * 13 * strips * cnt, 256, 0, stream>>>(
                        sb, prep + wtoff[b], fb, nullptr, M, M, Tin, Tout,
                        S_STR, spoff, F_STR, 480000, ott, strips, cnt, zpage);
                }
            }
        }
        done += NC;
    }
}